// Round 15
// baseline (44.970 us; speedup 1.0000x reference)
//
#include <hip/hip_runtime.h>
#include <hip/hip_bf16.h>

// Forward warp (bilinear splatting), per-tile gather-from-window.
//   img  [B=8, C=3, H=180, W=320] f32
//   flow [B=8, 2,  H=180, W=320] f32
//   scale=4 -> out [B, C, 720, 1280] f32
//
// R15 = R14 (40x32 tiles, 224 aligned strips, one strip/thread, margin 8)
// restructured as PERSISTENT 3-TILE BLOCKS: 1920 blocks x 3 consecutive-in-x
// tiles. Mechanisms: (1) 75% window overlap between consecutive tiles ->
// L1-warm loads for tiles 2,3; (2) block phases de-convoy after tile 1 ->
// load/atomic/store phases of different blocks interleave; (3) write-out
// fused with acc re-zero (no separate zero pass after tile 1).
// NO register double-buffering (R9's failure mode).
// |flow| > 8 pixels go through the EXACT-complement vectorized outlier
// kernel (separate dispatch AFTER tile stores; ordering requires it).

typedef float f32x4 __attribute__((ext_vector_type(4)));

#define B_ 8
#define C_ 3
#define H_ 180
#define W_ 320
#define HW_ (H_ * W_)
#define SCALE_ 4
#define Ho_ (H_ * SCALE_)            // 720
#define Wo_ (W_ * SCALE_)            // 1280
#define TH_ 40
#define TW_ 32
#define NTY_ (Ho_ / TH_)             // 18
#define NTX_ (Wo_ / TW_)             // 40
#define NTILES_ (B_ * NTY_ * NTX_)   // 5760
#define NPIX_ (B_ * H_ * W_)         // 460800

#define TPT_ 3                       // tiles per block (consecutive linear ids)
#define NBLK_ (NTILES_ / TPT_)       // 1920 (divisible by 8 -> bijective XCD swizzle)

#define MARGIN_ 8.0f
#define WIN_H_ 28                    // rows hb-9 .. hb+18
#define NSTRIP_W_ 8                  // strips of 4 cols: wb-12 .. wb+19
#define NSTRIPS_ (WIN_H_ * NSTRIP_W_)  // 224 (<= 256: one strip per thread)
#define PLANE_STRIDE_ 1284           // 1280+4: channel atomics -> distinct banks, 16B-aligned
#define LDS_FLOATS_ (C_ * PLANE_STRIDE_)   // 3852 floats = 15408 B

__global__ __launch_bounds__(256) void warp_tile_kernel(const float* __restrict__ img,
                                                        const float* __restrict__ flow,
                                                        float* __restrict__ out) {
    __shared__ __align__(16) float acc[LDS_FLOATS_];
    const int tid = threadIdx.x;

    // XCD-chunked swizzle over 1920 blocks (1920 % 8 == 0 -> bijective).
    const int g = (int)(blockIdx.x & 7) * (NBLK_ / 8) + (int)(blockIdx.x >> 3);

    // explicit zero before first tile only; afterwards writeout re-zeros
    for (int j = tid; j < LDS_FLOATS_ / 4; j += 256)
        *reinterpret_cast<f32x4*>(&acc[j * 4]) = (f32x4)(0.f);
    __syncthreads();

    for (int t = 0; t < TPT_; ++t) {
        const int tile = g * TPT_ + t;              // consecutive -> tx advances by 1
        const int tx = tile % NTX_;
        const int tt = tile / NTX_;
        const int ty = tt % NTY_;
        const int b  = tt / NTY_;
        const int px0 = tx * TW_;
        const int py0 = ty * TH_;

        const float* __restrict__ fxp  = flow + (size_t)(b * 2 + 0) * HW_;
        const float* __restrict__ fyp  = flow + (size_t)(b * 2 + 1) * HW_;
        const float* __restrict__ imgb = img + (size_t)b * C_ * HW_;

        const int hb = py0 >> 2;
        const int wb = px0 >> 2;

        // ---- phase 1: one aligned 4-px strip per thread, 5 f32x4 batched loads ----
        const int r  = tid / NSTRIP_W_;
        const int s  = tid - r * NSTRIP_W_;
        const int h  = hb - 9 + r;
        const int w0 = wb - 12 + 4 * s;
        const bool act = (tid < NSTRIPS_) &&
                         ((unsigned)h < (unsigned)H_) && ((unsigned)w0 < (unsigned)W_);
        const int hw = act ? (h * W_ + w0) : 0;
        f32x4 fx4 = *reinterpret_cast<const f32x4*>(&fxp[hw]);
        f32x4 fy4 = *reinterpret_cast<const f32x4*>(&fyp[hw]);
        f32x4 v04 = *reinterpret_cast<const f32x4*>(&imgb[hw]);
        f32x4 v14 = *reinterpret_cast<const f32x4*>(&imgb[HW_ + hw]);
        f32x4 v24 = *reinterpret_cast<const f32x4*>(&imgb[2 * HW_ + hw]);

        // ---- phase 2: predicate + hit-test + LDS accumulate ----
        if (act) {
            #pragma unroll
            for (int j = 0; j < 4; ++j) {
                float fx = fx4[j], fy = fy4[j];
                // Must be the EXACT complement of outlier_kernel's predicate.
                if (!(fabsf(fx) <= MARGIN_ && fabsf(fy) <= MARGIN_)) continue;

                float x = ((float)(w0 + j) + fx) * (float)SCALE_;
                float y = ((float)h + fy) * (float)SCALE_;
                float x0f = floorf(x), y0f = floorf(y);
                int ix0 = (int)x0f - px0;   // tile-local
                int iy0 = (int)y0f - py0;
                bool cx0 = (unsigned)ix0 < (unsigned)TW_;
                bool cx1 = (unsigned)(ix0 + 1) < (unsigned)TW_;
                bool cy0 = (unsigned)iy0 < (unsigned)TH_;
                bool cy1 = (unsigned)(iy0 + 1) < (unsigned)TH_;
                if (!((cx0 | cx1) & (cy0 | cy1))) continue;

                float ax = x - x0f, ay = y - y0f;
                float wxs[2] = {1.0f - ax, ax};
                float wys[2] = {1.0f - ay, ay};
                bool cxs[2] = {cx0, cx1};
                bool cys[2] = {cy0, cy1};
                float v0 = v04[j], v1 = v14[j], v2 = v24[j];
                #pragma unroll
                for (int ky = 0; ky < 2; ++ky) {
                    if (!cys[ky]) continue;
                    #pragma unroll
                    for (int kx = 0; kx < 2; ++kx) {
                        if (!cxs[kx]) continue;
                        float wt = wxs[kx] * wys[ky];
                        int la = (iy0 + ky) * TW_ + (ix0 + kx);
                        atomicAdd(&acc[la], v0 * wt);
                        atomicAdd(&acc[la + PLANE_STRIDE_], v1 * wt);
                        atomicAdd(&acc[la + 2 * PLANE_STRIDE_], v2 * wt);
                    }
                }
            }
        }
        __syncthreads();

        // ---- phase 3: exclusive nontemporal write-out fused with re-zero ----
        const size_t outb = (size_t)b * C_ * Ho_ * Wo_;
        const size_t chs  = (size_t)Ho_ * Wo_;
        const int F4_PER_PLANE = TH_ * TW_ / 4;        // 320
        const int F4_PER_ROW   = TW_ / 4;              // 8
        #pragma unroll
        for (int j = tid; j < C_ * F4_PER_PLANE; j += 256) {   // 960 total, <=4 iters
            int ch  = j / F4_PER_PLANE;
            int rem = j - ch * F4_PER_PLANE;
            int yy  = rem / F4_PER_ROW;
            int xx4 = rem - yy * F4_PER_ROW;
            float* lp = &acc[ch * PLANE_STRIDE_ + yy * TW_ + xx4 * 4];
            f32x4 v = *reinterpret_cast<const f32x4*>(lp);
            __builtin_nontemporal_store(v,
                reinterpret_cast<f32x4*>(
                    &out[outb + (size_t)ch * chs + (size_t)(py0 + yy) * Wo_ + px0 + xx4 * 4]));
            *reinterpret_cast<f32x4*>(lp) = (f32x4)(0.f);
        }
        __syncthreads();
    }
}

// Pixels with |flow| > MARGIN_: exact global-atomic splat (AFTER tile writes).
// Vectorized: 4 px/thread via f32x4 flow loads; fast path = all inliers.
__global__ __launch_bounds__(256) void outlier_kernel(const float* __restrict__ img,
                                                      const float* __restrict__ flow,
                                                      float* __restrict__ out) {
    int q = blockIdx.x * 256 + threadIdx.x;   // grid exactly NPIX_/4/256 = 450
    int idx = q * 4;
    int b = idx / HW_;                         // HW_ % 4 == 0 -> same b for all 4
    int hw = idx - b * HW_;
    f32x4 fx4 = *reinterpret_cast<const f32x4*>(&flow[(size_t)(b * 2 + 0) * HW_ + hw]);
    f32x4 fy4 = *reinterpret_cast<const f32x4*>(&flow[(size_t)(b * 2 + 1) * HW_ + hw]);

    bool ol[4];
    bool any = false;
    #pragma unroll
    for (int j = 0; j < 4; ++j) {
        ol[j] = !(fabsf(fx4[j]) <= MARGIN_ && fabsf(fy4[j]) <= MARGIN_);
        any |= ol[j];
    }
    if (!any) return;

    const float* imgb = img + (size_t)b * C_ * HW_;
    const size_t out_b = (size_t)b * C_ * Ho_ * Wo_;
    const size_t chs = (size_t)Ho_ * Wo_;
    #pragma unroll
    for (int j = 0; j < 4; ++j) {
        if (!ol[j]) continue;
        int hwj = hw + j;
        int h = hwj / W_;
        int w = hwj - h * W_;
        float x = ((float)w + fx4[j]) * (float)SCALE_;
        float y = ((float)h + fy4[j]) * (float)SCALE_;
        float x0f = floorf(x), y0f = floorf(y);
        float ax = x - x0f, ay = y - y0f;
        int ix0 = (int)x0f, iy0 = (int)y0f;
        float v0 = imgb[hwj];
        float v1 = imgb[HW_ + hwj];
        float v2 = imgb[2 * HW_ + hwj];
        float wxs[2] = {1.0f - ax, ax};
        float wys[2] = {1.0f - ay, ay};
        #pragma unroll
        for (int ky = 0; ky < 2; ++ky) {
            int yi = iy0 + ky;
            if ((unsigned)yi >= (unsigned)Ho_) continue;
            #pragma unroll
            for (int kx = 0; kx < 2; ++kx) {
                int xi = ix0 + kx;
                if ((unsigned)xi >= (unsigned)Wo_) continue;
                float wt = wxs[kx] * wys[ky];
                size_t base = out_b + (size_t)yi * Wo_ + (size_t)xi;
                atomicAdd(&out[base + 0 * chs], v0 * wt);
                atomicAdd(&out[base + 1 * chs], v1 * wt);
                atomicAdd(&out[base + 2 * chs], v2 * wt);
            }
        }
    }
}

// ---------------- fallback: naive global-atomic splat (scale != 4) ----------------
__global__ __launch_bounds__(256) void splat_naive(const float* __restrict__ img,
                                                   const float* __restrict__ flow,
                                                   const int* __restrict__ scale_p,
                                                   float* __restrict__ out) {
    int idx = blockIdx.x * blockDim.x + threadIdx.x;
    if (idx >= NPIX_) return;
    const int s = *scale_p;
    const int Ho = H_ * s, Wo = W_ * s;
    int w = idx % W_;
    int t = idx / W_;
    int h = t % H_;
    int b = t / H_;
    const int hw = h * W_ + w;
    float fx = flow[((b * 2 + 0) * H_) * W_ + hw];
    float fy = flow[((b * 2 + 1) * H_) * W_ + hw];
    float x = ((float)w + fx) * (float)s;
    float y = ((float)h + fy) * (float)s;
    float x0f = floorf(x), y0f = floorf(y);
    float ax = x - x0f, ay = y - y0f;
    int ix0 = (int)x0f, iy0 = (int)y0f;
    const size_t img_b = (size_t)b * C_ * HW_;
    float v0 = img[img_b + 0 * (size_t)HW_ + hw];
    float v1 = img[img_b + 1 * (size_t)HW_ + hw];
    float v2 = img[img_b + 2 * (size_t)HW_ + hw];
    const size_t out_b = (size_t)b * C_ * Ho * Wo;
    const size_t out_chs = (size_t)Ho * Wo;
    float wxs[2] = {1.0f - ax, ax};
    float wys[2] = {1.0f - ay, ay};
    #pragma unroll
    for (int ky = 0; ky < 2; ++ky) {
        int yi = iy0 + ky;
        if (yi < 0 || yi > Ho - 1) continue;
        #pragma unroll
        for (int kx = 0; kx < 2; ++kx) {
            int xi = ix0 + kx;
            if (xi < 0 || xi > Wo - 1) continue;
            float wt = wxs[kx] * wys[ky];
            size_t base = out_b + (size_t)yi * Wo + (size_t)xi;
            atomicAdd(&out[base + 0 * out_chs], v0 * wt);
            atomicAdd(&out[base + 1 * out_chs], v1 * wt);
            atomicAdd(&out[base + 2 * out_chs], v2 * wt);
        }
    }
}

extern "C" void kernel_launch(void* const* d_in, const int* in_sizes, int n_in,
                              void* d_out, int out_size, void* d_ws, size_t ws_size,
                              hipStream_t stream) {
    const float* img   = (const float*)d_in[0];
    const float* flow  = (const float*)d_in[1];
    const int*   scale = (const int*)d_in[2];
    float* out = (float*)d_out;

    const bool scale4 = (out_size == B_ * C_ * Ho_ * Wo_);

    if (scale4) {
        warp_tile_kernel<<<NBLK_, 256, 0, stream>>>(img, flow, out);
        outlier_kernel<<<NPIX_ / 4 / 256, 256, 0, stream>>>(img, flow, out);
    } else {
        (void)hipMemsetAsync(out, 0, (size_t)out_size * sizeof(float), stream);
        splat_naive<<<(NPIX_ + 255) / 256, 256, 0, stream>>>(img, flow, scale, out);
    }
}